// Round 9
// baseline (1958.303 us; speedup 1.0000x reference)
//
#include <hip/hip_runtime.h>

// PowerSpectrum: out[n, l*4096 + f*64 + g] = (2l+1)^{-1/2} * sum_m c_l[n,m,f]*c_l[n,m,g]
// N=10000, NF=64, l=0..5 (m sizes 1,3,5,7,9,11; 36 m-rows = 576 f4 = 9216B/sample)
//
// A/B round with counter visibility (harness poison fills ~620us hide short kernels):
//  D1 = baseline (block/sample) x2 reps  -> per-pass time + FETCH (RFO discriminator)
//  D2 = pipelined (8 samples/block, register prefetch, zero block turnover) x4 reps
// Both idempotent; final memory state = correct output.

#define NF 64
#define NL 6
#define SPB 8

typedef float f4 __attribute__((ext_vector_type(4)));

__constant__ float CG[NL] = {
    1.0f,                 // 1/sqrt(1)
    0.57735026918962576f, // 1/sqrt(3)
    0.44721359549995794f, // 1/sqrt(5)
    0.37796447300922722f, // 1/sqrt(7)
    0.33333333333333333f, // 1/sqrt(9)
    0.30151134457776363f  // 1/sqrt(11)
};

__device__ __forceinline__ void compute_store(const float* lds, int f0, int g4,
                                              float* outn) {
#pragma unroll
    for (int l = 0; l < NL; ++l) {
        const int nm = 2 * l + 1;
        const float* cl = lds + l * l * NF;
        const float cg = CG[l];

        f4 acc[4];
#pragma unroll
        for (int r = 0; r < 4; ++r) acc[r] = (f4)(0.f);

        for (int m = 0; m < nm; ++m) {
            const float* row = cl + m * NF;
            const f4 a = *(const f4*)(row + f0); // 16-lane broadcast
            const f4 b = *(const f4*)(row + g4); // stride-16B, cheap
#pragma unroll
            for (int r = 0; r < 4; ++r) acc[r] += a[r] * b;
        }

        float* po = outn + l * (NF * NF);
#pragma unroll
        for (int r = 0; r < 4; ++r) {
            f4 v = acc[r] * cg;
            *(f4*)(po + (size_t)(f0 + r) * NF + g4) = v;
        }
    }
}

// ---------------- D1: baseline, one block per sample ----------------
template <int REPS>
__global__ __launch_bounds__(256, 4) void ps_base(
    const float* __restrict__ c0, const float* __restrict__ c1,
    const float* __restrict__ c2, const float* __restrict__ c3,
    const float* __restrict__ c4, const float* __restrict__ c5,
    float* __restrict__ out)
{
    __shared__ float lds[2304];
    const float* cs[NL] = {c0, c1, c2, c3, c4, c5};
    const int n = blockIdx.x;
    const int tid = threadIdx.x;
    const int f0 = ((tid >> 4) << 2);
    const int g4 = ((tid & 15) << 2);
    float* outn = out + (size_t)n * (NL * NF * NF);

    for (int rep = 0; rep < REPS; ++rep) {
        __syncthreads(); // WAR vs previous rep's readers
#pragma unroll
        for (int l = 0; l < NL; ++l) {
            const int nm = 2 * l + 1;
            const f4* src = (const f4*)(cs[l] + (size_t)n * (nm * NF));
            f4* dst = (f4*)(lds + l * l * NF);
            const int cnt4 = nm * (NF / 4);
            for (int i = tid; i < cnt4; i += 256) dst[i] = src[i];
        }
        __syncthreads();
        asm volatile("" ::: "memory");
        compute_store(lds, f0, g4, outn);
    }
}

// ---------------- D2: pipelined, SPB samples per block ----------------
// LDS layout = concat of 6 blocks (block l at f4 index l*l*16, total 576 f4).
// Thread handles linear f4 indices {tid, tid+256, tid+512(<576 iff tid<64)}:
// per index, source = cs[l] + per-sample stride; prefetch sample s+1 into regs
// while computing sample s (HBM latency hides under compute+stores).
template <int REPS>
__global__ __launch_bounds__(256, 4) void ps_pipe(
    const float* __restrict__ c0, const float* __restrict__ c1,
    const float* __restrict__ c2, const float* __restrict__ c3,
    const float* __restrict__ c4, const float* __restrict__ c5,
    float* __restrict__ out, int N)
{
    __shared__ float lds[2304];
    const float* cs[NL] = {c0, c1, c2, c3, c4, c5};
    const int tid = threadIdx.x;

    // staging descriptors for k = 0,1,2 (k=2 valid iff tid<64)
    const bool k2 = (tid < 64);
    const f4* srcb[3];
    int sstr[3];
    f4* ldsp[3];
#pragma unroll
    for (int k = 0; k < 3; ++k) {
        const int i = k * 256 + tid;
        const int ic = (i < 576) ? i : 575;
        int l = 0;
        while ((l + 1) * (l + 1) * 16 <= ic) ++l; // cum f4 count = (l+1)^2*16
        const int off = ic - l * l * 16;
        srcb[k] = (const f4*)cs[l] + off;
        sstr[k] = (2 * l + 1) * 16; // f4 per sample in array l
        ldsp[k] = (f4*)lds + ic;
    }

    const int n0 = blockIdx.x * SPB;
    if (n0 >= N) return;
    const int f0 = ((tid >> 4) << 2);
    const int g4 = ((tid & 15) << 2);

    for (int rep = 0; rep < REPS; ++rep) {
        asm volatile("" ::: "memory");
        // prologue: load sample n0 into regs
        f4 r0 = srcb[0][(size_t)n0 * sstr[0]];
        f4 r1 = srcb[1][(size_t)n0 * sstr[1]];
        f4 r2 = k2 ? srcb[2][(size_t)n0 * sstr[2]] : (f4)(0.f);

        for (int s = 0; s < SPB; ++s) {
            const int n = n0 + s;
            if (n >= N) break;        // uniform per block
            __syncthreads();          // WAR: previous sample's LDS readers done
            *ldsp[0] = r0;
            *ldsp[1] = r1;
            if (k2) *ldsp[2] = r2;
            if (s + 1 < SPB && n + 1 < N) { // prefetch next sample (in flight
                const size_t np = n + 1;    //  during compute+stores below)
                r0 = srcb[0][np * sstr[0]];
                r1 = srcb[1][np * sstr[1]];
                if (k2) r2 = srcb[2][np * sstr[2]];
            }
            __syncthreads();          // LDS ready
            compute_store(lds, f0, g4, out + (size_t)n * (NL * NF * NF));
        }
    }
}

extern "C" void kernel_launch(void* const* d_in, const int* in_sizes, int n_in,
                              void* d_out, int out_size, void* d_ws, size_t ws_size,
                              hipStream_t stream) {
    const float* c0 = (const float*)d_in[0];
    const float* c1 = (const float*)d_in[1];
    const float* c2 = (const float*)d_in[2];
    const float* c3 = (const float*)d_in[3];
    const float* c4 = (const float*)d_in[4];
    const float* c5 = (const float*)d_in[5];
    float* outp = (float*)d_out;

    const int N = in_sizes[0] / NF; // c0 is (N, 1, 64)

    // D1: baseline x2 (per-pass time + RFO-discriminating FETCH_SIZE)
    hipLaunchKernelGGL((ps_base<2>), dim3(N), dim3(256), 0, stream,
                       c0, c1, c2, c3, c4, c5, outp);
    // D2: pipelined x4 (improvement candidate, counter-visible)
    hipLaunchKernelGGL((ps_pipe<4>), dim3((N + SPB - 1) / SPB), dim3(256), 0, stream,
                       c0, c1, c2, c3, c4, c5, outp, N);
}

// Round 10
// 1026.356 us; speedup vs baseline: 1.9080x; 1.9080x over previous
//
#include <hip/hip_runtime.h>

// PowerSpectrum: out[n, l*4096 + f*64 + g] = (2l+1)^{-1/2} * sum_m c_l[n,m,f]*c_l[n,m,g]
// N=10000, NF=64, l=0..5 (m sizes 1,3,5,7,9,11; 36 m-rows = 576 f4 = 9216B/sample)
//
// R9 counters: pipelined register-prefetch kernel = 206us/pass (5.0 TB/s, 79% of
// fill-rate), no store-RFO, occupancy 40%, VALU 12.6%. Residual gap = grid tail
// (1250 blocks on 1024 slots) + shallow store queues (4 blocks/CU).
// This round: persistent grid-stride, 8 blocks/CU (grid 2048, all resident,
// zero turnover), continuous prefetch pipeline across ~5 samples/block.

#define NF 64
#define NL 6
#define GRID 2048

typedef float f4 __attribute__((ext_vector_type(4)));

__constant__ float CG[NL] = {
    1.0f,                 // 1/sqrt(1)
    0.57735026918962576f, // 1/sqrt(3)
    0.44721359549995794f, // 1/sqrt(5)
    0.37796447300922722f, // 1/sqrt(7)
    0.33333333333333333f, // 1/sqrt(9)
    0.30151134457776363f  // 1/sqrt(11)
};

__device__ __forceinline__ void compute_store(const float* lds, int f0, int g4,
                                              float* outn) {
#pragma unroll
    for (int l = 0; l < NL; ++l) {
        const int nm = 2 * l + 1;
        const float* cl = lds + l * l * NF;
        const float cg = CG[l];

        f4 acc[4];
#pragma unroll
        for (int r = 0; r < 4; ++r) acc[r] = (f4)(0.f);

        for (int m = 0; m < nm; ++m) {
            const float* row = cl + m * NF;
            const f4 a = *(const f4*)(row + f0); // 16-lane broadcast
            const f4 b = *(const f4*)(row + g4); // stride-16B, cheap
#pragma unroll
            for (int r = 0; r < 4; ++r) acc[r] += a[r] * b;
        }

        float* po = outn + l * (NF * NF);
#pragma unroll
        for (int r = 0; r < 4; ++r) {
            f4 v = acc[r] * cg;
            *(f4*)(po + (size_t)(f0 + r) * NF + g4) = v;
        }
    }
}

// Persistent grid-stride: block b handles n = b, b+GRID, ... with register
// prefetch of sample n+GRID issued before compute of n (HBM latency hides
// under compute + 98KB of stores). LDS = concat of 6 l-blocks (l at f4 index
// l*l*16, 576 f4 total); thread stages f4 indices {tid, tid+256, tid+512<576}.
__global__ __launch_bounds__(256, 8) void ps_final(
    const float* __restrict__ c0, const float* __restrict__ c1,
    const float* __restrict__ c2, const float* __restrict__ c3,
    const float* __restrict__ c4, const float* __restrict__ c5,
    float* __restrict__ out, int N)
{
    __shared__ float lds[2304];
    const float* cs[NL] = {c0, c1, c2, c3, c4, c5};
    const int tid = threadIdx.x;

    // staging descriptors for k = 0,1,2 (k=2 valid iff tid<64)
    const bool k2 = (tid < 64);
    const f4* srcb[3];
    int sstr[3];
    f4* ldsp[3];
#pragma unroll
    for (int k = 0; k < 3; ++k) {
        const int i = k * 256 + tid;
        const int ic = (i < 576) ? i : 575;
        int l = 0;
        while ((l + 1) * (l + 1) * 16 <= ic) ++l; // cum f4 count = (l+1)^2*16
        const int off = ic - l * l * 16;
        srcb[k] = (const f4*)cs[l] + off;
        sstr[k] = (2 * l + 1) * 16; // f4 per sample in array l
        ldsp[k] = (f4*)lds + ic;
    }

    const int f0 = ((tid >> 4) << 2);
    const int g4 = ((tid & 15) << 2);

    int n = blockIdx.x;
    if (n >= N) return;

    // prologue: load first sample into regs
    f4 r0 = srcb[0][(size_t)n * sstr[0]];
    f4 r1 = srcb[1][(size_t)n * sstr[1]];
    f4 r2 = k2 ? srcb[2][(size_t)n * sstr[2]] : (f4)(0.f);

    for (; n < N; n += GRID) {
        __syncthreads(); // WAR: previous sample's LDS readers done
        *ldsp[0] = r0;
        *ldsp[1] = r1;
        if (k2) *ldsp[2] = r2;
        const int np = n + GRID;
        if (np < N) { // prefetch next sample; stays in flight during compute
            r0 = srcb[0][(size_t)np * sstr[0]];
            r1 = srcb[1][(size_t)np * sstr[1]];
            if (k2) r2 = srcb[2][(size_t)np * sstr[2]];
        }
        __syncthreads(); // LDS ready
        compute_store(lds, f0, g4, out + (size_t)n * (NL * NF * NF));
    }
}

extern "C" void kernel_launch(void* const* d_in, const int* in_sizes, int n_in,
                              void* d_out, int out_size, void* d_ws, size_t ws_size,
                              hipStream_t stream) {
    const float* c0 = (const float*)d_in[0];
    const float* c1 = (const float*)d_in[1];
    const float* c2 = (const float*)d_in[2];
    const float* c3 = (const float*)d_in[3];
    const float* c4 = (const float*)d_in[4];
    const float* c5 = (const float*)d_in[5];
    float* outp = (float*)d_out;

    const int N = in_sizes[0] / NF; // c0 is (N, 1, 64)

    hipLaunchKernelGGL(ps_final, dim3(GRID), dim3(256), 0, stream,
                       c0, c1, c2, c3, c4, c5, outp, N);
}